// Round 18
// baseline (227.846 us; speedup 1.0000x reference)
//
#include <hip/hip_runtime.h>
#include <math.h>

#define ND 11      // node feature dim
#define ED 5       // edge feature dim
#define NL 3       // NNConv layers
#define NSTEPS 3   // Set2Set steps
#define BN_EPS 1e-5f
#define NSLAB 32   // bn-stat slabs (spread same-address atomics)
#define CAP 64     // max LDS-staged nodes per graph in s2s (mean 20, 4sig+ margin; fallback beyond)

typedef _Float16 half8 __attribute__((ext_vector_type(8)));
typedef float f32x4 __attribute__((ext_vector_type(4)));

__device__ __forceinline__ float sigm(float x) { return 1.0f / (1.0f + expf(-x)); }

// ---------------- fused setup: enc | deg | ptr | packW | pack3 | zero ----------------
__global__ __launch_bounds__(256) void k_setup(
    const float* __restrict__ x, const float* __restrict__ Wenc,
    const float* __restrict__ benc, float* __restrict__ h0,
    _Float16* __restrict__ hh, int N,
    const int* __restrict__ dst, float* __restrict__ deg, int E,
    const int* __restrict__ batch, int* __restrict__ ptr, int B,
    const float* __restrict__ Wih, const float* __restrict__ Whh,
    const float* __restrict__ bih, const float* __restrict__ bhh,
    float* __restrict__ WihT, float* __restrict__ WhhT, float* __restrict__ gbias,
    const float* __restrict__ w2, const float* __restrict__ b2,
    _Float16* __restrict__ w2P, float* __restrict__ zp, long NZ,
    int nbEnc, int nbDeg, int nbPtr, int nbPackW, int nbPack3) {
  int bid = blockIdx.x;
  const int tid = threadIdx.x;
  if (bid < nbEnc) {  // node encoder: h0 = relu(x @ W_enc + b); also f16 copy
    int idx = bid * 256 + tid;
    if (idx < N * 64) {
      int n = idx >> 6, j = idx & 63;
      float acc = benc[j];
#pragma unroll
      for (int i = 0; i < ND; ++i) acc = fmaf(x[n * ND + i], Wenc[i * 64 + j], acc);
      float v = fmaxf(acc, 0.0f);
      h0[idx] = v;
      hh[idx] = (_Float16)v;
    }
    return;
  }
  bid -= nbEnc;
  if (bid < nbDeg) {  // in-degree histogram (deg zeroed by k_zdeg, prior node)
    int e = bid * 256 + tid;
    if (e < E) atomicAdd(&deg[dst[e]], 1.0f);
    return;
  }
  bid -= nbDeg;
  if (bid < nbPtr) {  // graph row pointers from sorted batch
    int n = bid * 256 + tid;
    if (n < N) {
      int b = batch[n];
      int pb = (n == 0) ? -1 : batch[n - 1];
      for (int g = pb + 1; g <= b; ++g) ptr[g] = n;
      if (n == N - 1)
        for (int g = b + 1; g <= B; ++g) ptr[g] = N;
    }
    return;
  }
  bid -= nbPtr;
  if (bid < nbPackW) {  // transpose LSTM weights
    int idx = bid * 256 + tid;
    if (idx < 128 * 256) {
      int i = idx >> 8, g = idx & 255;
      WihT[i * 256 + g] = Wih[g * 128 + i];
    } else if (idx < 192 * 256) {
      int j = idx - 128 * 256;
      int i = j >> 8, g = j & 255;
      WhhT[i * 256 + g] = Whh[g * 64 + i];
    } else if (idx < 192 * 256 + 256) {
      int g = idx - 192 * 256;
      gbias[g] = bih[g] + bhh[g];
    }
    return;
  }
  bid -= nbPackW;
  if (bid < nbPack3) {  // pack eW2 (+eb2 as slice 64) into MFMA-B frag layout
    int lay = bid / 130;
    int idx = (bid % 130) * 256 + tid;  // < 65*8*64 = 33280 exactly
    int l = idx & 63;
    int f = (idx >> 6) & 7;
    int s = idx >> 9;
    int nf = f >> 1, kf = f & 1;
    const float* srow = (s < 64) ? (w2 + (size_t)lay * 64 * 4096 + (size_t)s * 4096)
                                 : (b2 + (size_t)lay * 4096);
    int o = nf * 16 + (l & 15);
    int hb = kf * 32 + (l >> 4) * 8;
    half8 v;
#pragma unroll
    for (int j = 0; j < 8; ++j) v[j] = (_Float16)srow[(hb + j) * 64 + o];
    *(half8*)(w2P + ((size_t)lay * 65 * 8 * 64 + idx) * 8) = v;
    return;
  }
  bid -= nbPack3;
  {  // zero agg|bnslab region (deg excluded; zeroed by k_zdeg before this node)
    long i4 = ((long)bid * 256 + tid) * 4;
    if (i4 + 3 < NZ) *(float4*)(zp + i4) = make_float4(0.f, 0.f, 0.f, 0.f);
    else for (; i4 < NZ; ++i4) zp[i4] = 0.f;
  }
}

// deg must be zeroed BEFORE k_setup's histogram part -> separate tiny kernel, first node.
__global__ void k_zdeg(float* __restrict__ deg, int N) {
  int i = blockIdx.x * blockDim.x + threadIdx.x;
  if (i < N) deg[i] = 0.f;
}

// ---------------- single-block prefix scan of deg -> dptr / cursor (R4-R7 proven) ------
__global__ __launch_bounds__(256) void k_scan(const float* __restrict__ deg,
                                              int* __restrict__ dptr,
                                              int* __restrict__ cursor, int N) {
  __shared__ int wsum[4];
  __shared__ int s_carry;
  const int tid = threadIdx.x, lane = tid & 63, w = tid >> 6;
  if (tid == 0) s_carry = 0;
  __syncthreads();
  for (int base = 0; base < N; base += 1024) {
    int n0 = base + tid * 4;
    int v[4];
    int s = 0;
#pragma unroll
    for (int i = 0; i < 4; ++i) { v[i] = (n0 + i < N) ? (int)deg[n0 + i] : 0; s += v[i]; }
    int sc = s;  // inclusive wave scan
#pragma unroll
    for (int off = 1; off < 64; off <<= 1) {
      int t = __shfl_up(sc, off);
      if (lane >= off) sc += t;
    }
    if (lane == 63) wsum[w] = sc;
    __syncthreads();
    int wpre = 0;
    for (int ww = 0; ww < w; ++ww) wpre += wsum[ww];
    int excl = s_carry + wpre + sc - s;
#pragma unroll
    for (int i = 0; i < 4; ++i) {
      if (n0 + i < N) { dptr[n0 + i] = excl; cursor[n0 + i] = excl; }
      excl += v[i];
    }
    __syncthreads();
    if (tid == 255) s_carry += wsum[0] + wsum[1] + wsum[2] + wsum[3];
    __syncthreads();
  }
  if (threadIdx.x == 0) dptr[N] = s_carry;
}

// ---------------- scatter: dst-sorted edge permutation + permuted src/dst --------------
__global__ void k_fill(const int* __restrict__ dst, const int* __restrict__ src,
                       int* __restrict__ cursor, int* __restrict__ perm,
                       int* __restrict__ srcP, int* __restrict__ dstP, int E) {
  int e = blockIdx.x * blockDim.x + threadIdx.x;
  if (e < E) {
    int d = dst[e];
    int slot = atomicAdd(&cursor[d], 1);
    perm[slot] = e;
    srcP[slot] = src[e];
    dstP[slot] = d;
  }
}

// ---------------- materialize h_l = relu(bn(hn_{l-1})) + h_{l-1} (fp32 + f16) ---------
__global__ __launch_bounds__(256) void k_hmat(
    const float* __restrict__ hn, const float* __restrict__ hp,
    const float* __restrict__ slab, const float* __restrict__ gm,
    const float* __restrict__ bt, float* __restrict__ hout,
    _Float16* __restrict__ hh, int N) {
  __shared__ float stats[128];
  const int tid = threadIdx.x;
  if (tid < 128) {
    float s = 0.f;
#pragma unroll
    for (int sl = 0; sl < NSLAB; ++sl) s += slab[sl * 128 + tid];
    stats[tid] = s;
  }
  __syncthreads();
  int idx = blockIdx.x * 256 + tid;
  if (idx >= N * 64) return;
  int o = idx & 63;
  float invN = 1.0f / (float)N;
  float mu = stats[o] * invN;
  float var = stats[64 + o] * invN - mu * mu;
  float rs = rsqrtf(var + BN_EPS) * gm[o];
  float v = fmaxf((hn[idx] - mu) * rs + bt[o], 0.f) + hp[idx];
  hout[idx] = v;
  hh[idx] = (_Float16)v;
}

// ---------------- FUSED NNConv message (MFMA) + per-node aggregation (R16-proven) ------
__global__ __launch_bounds__(512, 8) void k_msgagg(
    const float* __restrict__ ea, const int* __restrict__ perm,
    const float* __restrict__ eW1l, const float* __restrict__ eb1l,
    const _Float16* __restrict__ hh, const int* __restrict__ srcP,
    const int* __restrict__ dstP, const int* __restrict__ dptr,
    const _Float16* __restrict__ w2P, float* __restrict__ agg, int E, int N) {
  __shared__ _Float16 e1t[65][64];  // f16; k=64 is bias slice
  __shared__ float tileH[64][66];   // full-K message tile
  __shared__ float eat[64][ED];
  __shared__ float w1s[ED * 64];
  __shared__ float b1s[64];

  const int tid = threadIdx.x;
  const int wid = tid >> 6, l = tid & 63;
  const int mh = wid >> 2, quad = wid & 3;   // wave = (m-half, feature-quad)
  const int lo = l & 15, lg = l >> 4;
  const int e0 = blockIdx.x * 64;

  // ---- A-frags FIRST (2 m-groups/wave): latency hides under staging + e1 MLP ----
  half8 hsf[2][2];
#pragma unroll
  for (int mm = 0; mm < 2; ++mm) {
    int s = e0 + (mh * 2 + mm) * 16 + lo;
    if (s < E) {
      const _Float16* hr = hh + (size_t)srcP[s] * 64;
      hsf[mm][0] = *(const half8*)(hr + lg * 8);
      hsf[mm][1] = *(const half8*)(hr + 32 + lg * 8);
    } else {
      half8 z = {0, 0, 0, 0, 0, 0, 0, 0};
      hsf[mm][0] = z;
      hsf[mm][1] = z;
    }
  }

  // ---- stage w1/b1 + ea gather ----
  if (tid < ED * 64) w1s[tid] = eW1l[tid];
  else if (tid < ED * 64 + 64) b1s[tid - ED * 64] = eb1l[tid - ED * 64];
  if (tid >= 448) {
    int s = e0 + (tid - 448);
    if (s < E) {
      int e = perm[s];
#pragma unroll
      for (int i = 0; i < ED; ++i) eat[tid - 448][i] = ea[(size_t)e * ED + i];
    } else {
#pragma unroll
      for (int i = 0; i < ED; ++i) eat[tid - 448][i] = 0.f;
    }
  }
  __syncthreads();

  // ---- edge MLP layer1 into LDS: e1t[k][edge] (f16) ----
  for (int idx = tid; idx < 65 * 64; idx += 512) {
    int el = idx & 63, k = idx >> 6;
    float v = 1.0f;  // bias slice k=64
    if (k < 64) {
      v = b1s[k];
#pragma unroll
      for (int i = 0; i < ED; ++i) v = fmaf(eat[el][i], w1s[i * 64 + k], v);
      v = fmaxf(v, 0.f);
    }
    e1t[k][el] = (_Float16)v;
  }
  __syncthreads();  // e1t ready

  // ---- K-loop: ALL 65 slices, 4-deep B prefetch ring, full-K accumulation ----
  f32x4 acc[2] = {};
  const half8* wp = (const half8*)w2P;  // [65][8][64] half8 units
  half8 Br[4][2];
#pragma unroll
  for (int d = 0; d < 4; ++d) {
    Br[d][0] = wp[((size_t)d * 8 + quad * 2 + 0) * 64 + l];
    Br[d][1] = wp[((size_t)d * 8 + quad * 2 + 1) * 64 + l];
  }
  const int mb0 = (mh * 2 + 0) * 16 + lo;
  const int mb1 = (mh * 2 + 1) * 16 + lo;
#pragma unroll 65
  for (int k = 0; k < 65; ++k) {
    const int d = k & 3;  // static under full unroll
    const _Float16 s0 = e1t[k][mb0];
    const _Float16 s1 = e1t[k][mb1];
    half8 A00 = hsf[0][0] * s0;
    half8 A01 = hsf[0][1] * s0;
    half8 A10 = hsf[1][0] * s1;
    half8 A11 = hsf[1][1] * s1;
    acc[0] = __builtin_amdgcn_mfma_f32_16x16x32_f16(A00, Br[d][0], acc[0], 0, 0, 0);
    acc[0] = __builtin_amdgcn_mfma_f32_16x16x32_f16(A01, Br[d][1], acc[0], 0, 0, 0);
    acc[1] = __builtin_amdgcn_mfma_f32_16x16x32_f16(A10, Br[d][0], acc[1], 0, 0, 0);
    acc[1] = __builtin_amdgcn_mfma_f32_16x16x32_f16(A11, Br[d][1], acc[1], 0, 0, 0);
    if (k + 4 < 65) {  // refill slot d, lands 4 iterations ahead
      Br[d][0] = wp[((size_t)(k + 4) * 8 + quad * 2 + 0) * 64 + l];
      Br[d][1] = wp[((size_t)(k + 4) * 8 + quad * 2 + 1) * 64 + l];
    }
  }

  // ---- store msg quadrant (full-K sums; D layout: col=l&15, row=(l>>4)*4+reg) ----
#pragma unroll
  for (int mm = 0; mm < 2; ++mm)
#pragma unroll
    for (int r = 0; r < 4; ++r)
      tileH[(mh * 2 + mm) * 16 + lg * 4 + r][quad * 16 + lo] = acc[mm][r];
  __syncthreads();

  // ---- per-node aggregation from LDS (plain store interior, atomic boundary) ----
  const int o = tid & 63, r8 = tid >> 6;
  const int lastSlot = (e0 + 63 < E) ? (e0 + 63) : (E - 1);
  int nLo = dstP[e0], nHi = dstP[lastSlot];
  nLo = (nLo < 0) ? 0 : ((nLo >= N) ? N - 1 : nLo);   // clamp: poisoned-replay safety
  nHi = (nHi < 0) ? 0 : ((nHi >= N) ? N - 1 : nHi);
  for (int nn = nLo + r8; nn <= nHi; nn += 8) {
    int d0 = dptr[nn], d1 = dptr[nn + 1];
    d0 = (d0 < 0) ? 0 : d0;
    d1 = (d1 > E) ? E : d1;
    int j0 = (d0 > e0) ? d0 : e0;
    int j1 = (d1 < e0 + 64) ? d1 : (e0 + 64);
    float sum = 0.f;
    for (int j = j0; j < j1; ++j) sum += tileH[j - e0][o];
    float* dp = agg + (size_t)nn * 64 + o;
    if (d0 < e0 || d1 > e0 + 64) { if (j1 > j0) atomicAdd(dp, sum); }
    else *dp = sum;
  }
}

// ---------------- update_l: hn_l = agg/deg + h_l@root + cbias ; stats_l; zero agg ------
__global__ __launch_bounds__(256) void k_update(
    const float* __restrict__ hcur, float* __restrict__ agg,
    const float* __restrict__ deg, const float* __restrict__ root,
    const float* __restrict__ cb, float* __restrict__ hn_out,
    float* __restrict__ slab_out, int N) {
  __shared__ float hrow[16][64];
  __shared__ float red[2][256];
  const int tid = threadIdx.x, o = tid & 63, r = tid >> 6;
  const int nb = blockIdx.x * 16;
#pragma unroll
  for (int ii = 0; ii < 4; ++ii) {
    int n = nb + ii * 4 + r;
    hrow[ii * 4 + r][o] = (n < N) ? hcur[(size_t)n * 64 + o] : 0.f;
  }
  __syncthreads();
  float acc[4] = {0.f, 0.f, 0.f, 0.f};
  for (int c = 0; c < 64; ++c) {
    float rv = root[c * 64 + o];
#pragma unroll
    for (int ii = 0; ii < 4; ++ii) acc[ii] = fmaf(hrow[ii * 4 + r][c], rv, acc[ii]);
  }
  float s = 0.f, ss = 0.f;
  const float cbv = cb[o];
#pragma unroll
  for (int ii = 0; ii < 4; ++ii) {
    int n = nb + ii * 4 + r;
    if (n < N) {
      float a = agg[(size_t)n * 64 + o];
      agg[(size_t)n * 64 + o] = 0.f;  // reset for next layer's atomics
      float v = acc[ii] + cbv + a / fmaxf(deg[n], 1.0f);
      hn_out[(size_t)n * 64 + o] = v;
      s += v;
      ss += v * v;
    }
  }
  red[0][tid] = s;
  red[1][tid] = ss;
  __syncthreads();
  if (r == 0) {
    float t0 = red[0][o] + red[0][64 + o] + red[0][128 + o] + red[0][192 + o];
    float t1 = red[1][o] + red[1][64 + o] + red[1][128 + o] + red[1][192 + o];
    float* sl = slab_out + (size_t)(blockIdx.x & (NSLAB - 1)) * 128;
    atomicAdd(&sl[o], t0);
    atomicAdd(&sl[64 + o], t1);
  }
}

// ---------------- fused Set2Set: LDS-staged attention (CAP=64), all steps + head -------
__global__ __launch_bounds__(256) void k_s2s_all(
    const float* __restrict__ hn2, const float* __restrict__ h2,
    const float* __restrict__ slab2, const float* __restrict__ gm,
    const float* __restrict__ bt, const int* __restrict__ ptr,
    const float* __restrict__ WihT, const float* __restrict__ WhhT,
    const float* __restrict__ gbias,
    const float* __restrict__ hW1, const float* __restrict__ hb1,
    const float* __restrict__ hW2, const float* __restrict__ hb2,
    const float* __restrict__ hW3, const float* __restrict__ hb3,
    float* __restrict__ out, int N) {
  __shared__ float hvs[CAP * 65];   // staged node features (pad 65 -> conflict-free)
  __shared__ float stats[128];
  __shared__ float mu_s[64], rs_s[64], bt_s[64];
  __shared__ float qs[128];
  __shared__ float hlc[64], clc[64];
  __shared__ float gates[256];
  __shared__ float qv[64];
  __shared__ float ev[256];
  __shared__ float av[CAP];
  __shared__ float redM[4], redS[4];
  __shared__ float redR[4][64];
  __shared__ float z1[64], z2[32];
  const int b = blockIdx.x, tid = threadIdx.x;
  const int wid = tid >> 6, lane = tid & 63;

  if (tid < 128) {
    float s = 0.f;
#pragma unroll
    for (int sl = 0; sl < NSLAB; ++sl) s += slab2[sl * 128 + tid];
    stats[tid] = s;
    qs[tid] = 0.f;
  }
  if (tid < 64) { hlc[tid] = 0.f; clc[tid] = 0.f; }
  __syncthreads();
  if (tid < 64) {
    float invN = 1.0f / (float)N;
    float mu = stats[tid] * invN;
    float var = stats[64 + tid] * invN - mu * mu;
    mu_s[tid] = mu;
    rs_s[tid] = rsqrtf(var + BN_EPS) * gm[tid];
    bt_s[tid] = bt[tid];
  }
  __syncthreads();
  int beg = ptr[b], end = ptr[b + 1];
  if (beg < 0) beg = 0;              // poisoned-replay safety
  if (end > N) end = N;
  const int nn = (end > beg) ? (end - beg) : 0;
  const bool big = nn > CAP;

  if (!big) {  // stage hv once: h3[n] = relu(bn(hn2)) + h2, reused across all steps
    for (int idx = tid; idx < nn * 64; idx += 256) {
      int n = idx >> 6, o = idx & 63;
      size_t g = (size_t)(beg + n) * 64 + o;
      hvs[n * 65 + o] = fmaxf((hn2[g] - mu_s[o]) * rs_s[o] + bt_s[o], 0.f) + h2[g];
    }
  }
  __syncthreads();

  for (int step = 0; step < NSTEPS; ++step) {
    // ---- LSTM ----
    float g = gbias[tid];
    for (int i = 0; i < 128; ++i) g = fmaf(qs[i], WihT[i * 256 + tid], g);
    for (int i = 0; i < 64; ++i) g = fmaf(hlc[i], WhhT[i * 256 + tid], g);
    gates[tid] = g;
    __syncthreads();
    if (tid < 64) {
      float ig = sigm(gates[tid]);
      float fg = sigm(gates[64 + tid]);
      float gg = tanhf(gates[128 + tid]);
      float og = sigm(gates[192 + tid]);
      float c = fg * clc[tid] + ig * gg;
      clc[tid] = c;
      float hnew = og * tanhf(c);
      hlc[tid] = hnew;
      qv[tid] = hnew;
    }
    __syncthreads();

    if (!big) {
      // ---- lane-per-node attention from LDS ----
      if (tid < nn) {
        float s = 0.f;
#pragma unroll 8
        for (int o = 0; o < 64; ++o) s = fmaf(hvs[tid * 65 + o], qv[o], s);
        ev[tid] = s;
      } else {
        ev[tid] = -INFINITY;
      }
      __syncthreads();
      if (tid < 64) {
        float m4 = fmaxf(fmaxf(ev[tid], ev[64 + tid]), fmaxf(ev[128 + tid], ev[192 + tid]));
#pragma unroll
        for (int s = 32; s; s >>= 1) m4 = fmaxf(m4, __shfl_xor(m4, s));
        if (tid == 0) redM[0] = m4;
      }
      __syncthreads();
      const float m = redM[0];
      float a = 0.f;
      if (tid < nn) { a = expf(ev[tid] - m); av[tid] = a; }
      __syncthreads();          // av writes done before reuse of ev
      ev[tid] = a;
      __syncthreads();
      if (tid < 64) {
        float s4 = ev[tid] + ev[64 + tid] + ev[128 + tid] + ev[192 + tid];
#pragma unroll
        for (int s = 32; s; s >>= 1) s4 += __shfl_xor(s4, s);
        if (tid == 0) redS[0] = s4;
      }
      __syncthreads();
      const float sden = redS[0];
      if (tid < 128) {
        if (tid < 64) {
          qs[tid] = qv[tid];
        } else {
          int o = tid - 64;
          float r = 0.f;
          for (int n = 0; n < nn; ++n) r = fmaf(av[n], hvs[n * 65 + o], r);
          qs[tid] = (nn > 0) ? r / sden : 0.f;
        }
      }
      __syncthreads();
    } else {
      // ---- fallback: global-read path (graphs > CAP nodes) ----
      const float q = qv[lane];
      float mw = -INFINITY;
      for (int n = beg + wid; n < end; n += 4) {
        float hv = fmaxf((hn2[(size_t)n * 64 + lane] - mu_s[lane]) * rs_s[lane] + bt_s[lane],
                         0.f) + h2[(size_t)n * 64 + lane];
        float p = hv * q;
#pragma unroll
        for (int s = 32; s; s >>= 1) p += __shfl_xor(p, s);
        mw = fmaxf(mw, p);
      }
      if (lane == 0) redM[wid] = mw;
      __syncthreads();
      const float m = fmaxf(fmaxf(redM[0], redM[1]), fmaxf(redM[2], redM[3]));
      float ssum = 0.f, racc = 0.f;
      for (int n = beg + wid; n < end; n += 4) {
        float hv = fmaxf((hn2[(size_t)n * 64 + lane] - mu_s[lane]) * rs_s[lane] + bt_s[lane],
                         0.f) + h2[(size_t)n * 64 + lane];
        float p = hv * q;
#pragma unroll
        for (int s = 32; s; s >>= 1) p += __shfl_xor(p, s);
        float a = expf(p - m);
        ssum += a;
        racc = fmaf(a, hv, racc);
      }
      if (lane == 0) redS[wid] = ssum;
      redR[wid][lane] = racc;
      __syncthreads();
      if (tid < 128) {
        if (tid < 64) {
          qs[tid] = qv[tid];
        } else {
          int o2 = tid - 64;
          float rsum = redR[0][o2] + redR[1][o2] + redR[2][o2] + redR[3][o2];
          float sd = redS[0] + redS[1] + redS[2] + redS[3];
          qs[tid] = (end > beg) ? rsum / sd : 0.0f;
        }
      }
      __syncthreads();
    }
  }

  // ---- regression head (reads final q_star in qs) ----
  if (tid < 64) {
    float a = hb1[tid];
    for (int i = 0; i < 128; ++i) a = fmaf(qs[i], hW1[i * 64 + tid], a);
    z1[tid] = fmaxf(a, 0.0f);
  }
  __syncthreads();
  if (tid < 32) {
    float a2 = hb2[tid];
    for (int i = 0; i < 64; ++i) a2 = fmaf(z1[i], hW2[i * 32 + tid], a2);
    z2[tid] = fmaxf(a2, 0.0f);
  }
  __syncthreads();
  if (tid < 64) {
    float p = (tid < 32) ? z2[tid] * hW3[tid] : 0.0f;
#pragma unroll
    for (int s = 32; s; s >>= 1) p += __shfl_xor(p, s);
    if (tid == 0) out[b] = p + hb3[0];
  }
}

extern "C" void kernel_launch(void* const* d_in, const int* in_sizes, int n_in,
                              void* d_out, int out_size, void* d_ws, size_t ws_size,
                              hipStream_t stream) {
  const float* x = (const float*)d_in[0];
  const int* eidx = (const int*)d_in[1];
  const float* ea = (const float*)d_in[2];
  const int* batch = (const int*)d_in[3];
  const float* Wenc = (const float*)d_in[4];
  const float* benc = (const float*)d_in[5];
  const float* eW1 = (const float*)d_in[6];
  const float* eb1 = (const float*)d_in[7];
  const float* eW2 = (const float*)d_in[8];
  const float* eb2 = (const float*)d_in[9];
  const float* root = (const float*)d_in[10];
  const float* cbias = (const float*)d_in[11];
  const float* gamma = (const float*)d_in[12];
  const float* beta = (const float*)d_in[13];
  const float* Wih = (const float*)d_in[14];
  const float* Whh = (const float*)d_in[15];
  const float* bih = (const float*)d_in[16];
  const float* bhh = (const float*)d_in[17];
  const float* hW1 = (const float*)d_in[18];
  const float* hb1 = (const float*)d_in[19];
  const float* hW2 = (const float*)d_in[20];
  const float* hb2 = (const float*)d_in[21];
  const float* hW3 = (const float*)d_in[22];
  const float* hb3 = (const float*)d_in[23];

  const int N = in_sizes[0] / ND;
  const int E = in_sizes[1] / 2;
  const int B = out_size;
  const int* srcp = eidx;
  const int* dstp = eidx + E;
  const int Etiles = (E + 63) / 64;

  // ---- workspace layout: deg | [zeroed: agg|bnslab] | rest ----
  float* ws = (float*)d_ws;
  float* deg = ws;                                     // N (zeroed by k_zdeg)
  float* agg = deg + N;                                // N*64
  float* bnslab = agg + (size_t)N * 64;                // NL * NSLAB * 128
  const long NZ = (long)((size_t)N * 64 + NL * NSLAB * 128);
  float* h0 = bnslab + NL * NSLAB * 128;               // N*64
  float* h1 = h0 + (size_t)N * 64;                     // N*64
  float* h2 = h1 + (size_t)N * 64;                     // N*64
  float* hn0 = h2 + (size_t)N * 64;                    // N*64
  float* hn1 = hn0 + (size_t)N * 64;                   // N*64
  float* hn2 = hn1 + (size_t)N * 64;                   // N*64
  _Float16* w2P = (_Float16*)(hn2 + (size_t)N * 64);   // 3 * 65*8*64*8 f16
  _Float16* hhalf = w2P + (size_t)3 * 65 * 8 * 64 * 8; // N*64 f16
  float* WihT = (float*)(hhalf + (size_t)N * 64);      // 128*256
  float* WhhT = WihT + 128 * 256;                      // 64*256
  float* gbias = WhhT + 64 * 256;                      // 256
  int* dptr = (int*)(gbias + 256);                     // N+1
  int* cursor = dptr + N + 1;                          // N
  int* perm = cursor + N;                              // E
  int* srcP = perm + E;                                // E
  int* dstP = srcP + E;                                // E
  int* ptr = dstP + E;                                 // B+1

  const int nbEnc = (N * 64 + 255) / 256;
  const int nbDeg = (E + 255) / 256;
  const int nbPtr = (N + 255) / 256;
  const int nbPackW = (192 * 256 + 256 + 255) / 256;
  const int nbPack3 = 130 * NL;
  const int nbZero = (int)((NZ / 4 + 255) / 256);

  k_zdeg<<<(N + 255) / 256, 256, 0, stream>>>(deg, N);
  k_setup<<<nbEnc + nbDeg + nbPtr + nbPackW + nbPack3 + nbZero, 256, 0, stream>>>(
      x, Wenc, benc, h0, hhalf, N, dstp, deg, E, batch, ptr, B,
      Wih, Whh, bih, bhh, WihT, WhhT, gbias, eW2, eb2, w2P, agg, NZ,
      nbEnc, nbDeg, nbPtr, nbPackW, nbPack3);
  k_scan<<<1, 256, 0, stream>>>(deg, dptr, cursor, N);
  k_fill<<<(E + 255) / 256, 256, 0, stream>>>(dstp, srcp, cursor, perm, srcP, dstP, E);

  float* hbuf[3] = {h0, h1, h2};
  float* hnbuf[3] = {hn0, hn1, hn2};
  for (int l = 0; l < NL; ++l) {
    float* slab_l = bnslab + (size_t)l * NSLAB * 128;
    const _Float16* w2_l = w2P + (size_t)l * 65 * 8 * 64 * 8;
    if (l > 0) {
      k_hmat<<<(N * 64 + 255) / 256, 256, 0, stream>>>(
          hnbuf[l - 1], hbuf[l - 1], bnslab + (size_t)(l - 1) * NSLAB * 128,
          gamma + (l - 1) * 64, beta + (l - 1) * 64, hbuf[l], hhalf, N);
    }
    k_msgagg<<<Etiles, 512, 0, stream>>>(ea, perm, eW1 + (size_t)l * ED * 64,
                                         eb1 + (size_t)l * 64, hhalf, srcP, dstP, dptr,
                                         w2_l, agg, E, N);
    k_update<<<(N + 15) / 16, 256, 0, stream>>>(hbuf[l], agg, deg,
                                                root + (size_t)l * 64 * 64,
                                                cbias + l * 64, hnbuf[l], slab_l, N);
  }

  k_s2s_all<<<B, 256, 0, stream>>>(hn2, h2, bnslab + (size_t)2 * NSLAB * 128,
                                   gamma + 2 * 64, beta + 2 * 64, ptr, WihT, WhhT, gbias,
                                   hW1, hb1, hW2, hb2, hW3, hb3, (float*)d_out, N);
}

// Round 19
// 183.928 us; speedup vs baseline: 1.2388x; 1.2388x over previous
//
#include <hip/hip_runtime.h>
#include <math.h>

#define ND 11      // node feature dim
#define ED 5       // edge feature dim
#define NL 3       // NNConv layers
#define NSTEPS 3   // Set2Set steps
#define BN_EPS 1e-5f
#define NSLAB 32   // bn-stat slabs (spread same-address atomics)
#define CAP 256    // max LDS-staged nodes per graph in s2s. NOTE: CAP=64 regressed s2s
                   // 2.6x (R18) despite smaller LDS - the 70KB footprint enforces an even
                   // 2-blocks/CU spread of the 500 blocks. Keep 256.

typedef _Float16 half8 __attribute__((ext_vector_type(8)));
typedef float f32x4 __attribute__((ext_vector_type(4)));

__device__ __forceinline__ float sigm(float x) { return 1.0f / (1.0f + expf(-x)); }

// ---------------- fused setup: enc | deg | ptr | packW | pack3 | zero ----------------
__global__ __launch_bounds__(256) void k_setup(
    const float* __restrict__ x, const float* __restrict__ Wenc,
    const float* __restrict__ benc, float* __restrict__ h0,
    _Float16* __restrict__ hh, int N,
    const int* __restrict__ dst, float* __restrict__ deg, int E,
    const int* __restrict__ batch, int* __restrict__ ptr, int B,
    const float* __restrict__ Wih, const float* __restrict__ Whh,
    const float* __restrict__ bih, const float* __restrict__ bhh,
    float* __restrict__ WihT, float* __restrict__ WhhT, float* __restrict__ gbias,
    const float* __restrict__ w2, const float* __restrict__ b2,
    _Float16* __restrict__ w2P, float* __restrict__ zp, long NZ,
    int nbEnc, int nbDeg, int nbPtr, int nbPackW, int nbPack3) {
  int bid = blockIdx.x;
  const int tid = threadIdx.x;
  if (bid < nbEnc) {  // node encoder: h0 = relu(x @ W_enc + b); also f16 copy
    int idx = bid * 256 + tid;
    if (idx < N * 64) {
      int n = idx >> 6, j = idx & 63;
      float acc = benc[j];
#pragma unroll
      for (int i = 0; i < ND; ++i) acc = fmaf(x[n * ND + i], Wenc[i * 64 + j], acc);
      float v = fmaxf(acc, 0.0f);
      h0[idx] = v;
      hh[idx] = (_Float16)v;
    }
    return;
  }
  bid -= nbEnc;
  if (bid < nbDeg) {  // in-degree histogram (deg zeroed by k_zdeg, prior node)
    int e = bid * 256 + tid;
    if (e < E) atomicAdd(&deg[dst[e]], 1.0f);
    return;
  }
  bid -= nbDeg;
  if (bid < nbPtr) {  // graph row pointers from sorted batch
    int n = bid * 256 + tid;
    if (n < N) {
      int b = batch[n];
      int pb = (n == 0) ? -1 : batch[n - 1];
      for (int g = pb + 1; g <= b; ++g) ptr[g] = n;
      if (n == N - 1)
        for (int g = b + 1; g <= B; ++g) ptr[g] = N;
    }
    return;
  }
  bid -= nbPtr;
  if (bid < nbPackW) {  // transpose LSTM weights
    int idx = bid * 256 + tid;
    if (idx < 128 * 256) {
      int i = idx >> 8, g = idx & 255;
      WihT[i * 256 + g] = Wih[g * 128 + i];
    } else if (idx < 192 * 256) {
      int j = idx - 128 * 256;
      int i = j >> 8, g = j & 255;
      WhhT[i * 256 + g] = Whh[g * 64 + i];
    } else if (idx < 192 * 256 + 256) {
      int g = idx - 192 * 256;
      gbias[g] = bih[g] + bhh[g];
    }
    return;
  }
  bid -= nbPackW;
  if (bid < nbPack3) {  // pack eW2 (+eb2 as slice 64) into MFMA-B frag layout
    int lay = bid / 130;
    int idx = (bid % 130) * 256 + tid;  // < 65*8*64 = 33280 exactly
    int l = idx & 63;
    int f = (idx >> 6) & 7;
    int s = idx >> 9;
    int nf = f >> 1, kf = f & 1;
    const float* srow = (s < 64) ? (w2 + (size_t)lay * 64 * 4096 + (size_t)s * 4096)
                                 : (b2 + (size_t)lay * 4096);
    int o = nf * 16 + (l & 15);
    int hb = kf * 32 + (l >> 4) * 8;
    half8 v;
#pragma unroll
    for (int j = 0; j < 8; ++j) v[j] = (_Float16)srow[(hb + j) * 64 + o];
    *(half8*)(w2P + ((size_t)lay * 65 * 8 * 64 + idx) * 8) = v;
    return;
  }
  bid -= nbPack3;
  {  // zero agg|bnslab region (deg excluded; zeroed by k_zdeg before this node)
    long i4 = ((long)bid * 256 + tid) * 4;
    if (i4 + 3 < NZ) *(float4*)(zp + i4) = make_float4(0.f, 0.f, 0.f, 0.f);
    else for (; i4 < NZ; ++i4) zp[i4] = 0.f;
  }
}

// deg must be zeroed BEFORE k_setup's histogram part -> separate tiny kernel, first node.
__global__ void k_zdeg(float* __restrict__ deg, int N) {
  int i = blockIdx.x * blockDim.x + threadIdx.x;
  if (i < N) deg[i] = 0.f;
}

// ---------------- single-block prefix scan of deg -> dptr / cursor (R4-R7 proven) ------
__global__ __launch_bounds__(256) void k_scan(const float* __restrict__ deg,
                                              int* __restrict__ dptr,
                                              int* __restrict__ cursor, int N) {
  __shared__ int wsum[4];
  __shared__ int s_carry;
  const int tid = threadIdx.x, lane = tid & 63, w = tid >> 6;
  if (tid == 0) s_carry = 0;
  __syncthreads();
  for (int base = 0; base < N; base += 1024) {
    int n0 = base + tid * 4;
    int v[4];
    int s = 0;
#pragma unroll
    for (int i = 0; i < 4; ++i) { v[i] = (n0 + i < N) ? (int)deg[n0 + i] : 0; s += v[i]; }
    int sc = s;  // inclusive wave scan
#pragma unroll
    for (int off = 1; off < 64; off <<= 1) {
      int t = __shfl_up(sc, off);
      if (lane >= off) sc += t;
    }
    if (lane == 63) wsum[w] = sc;
    __syncthreads();
    int wpre = 0;
    for (int ww = 0; ww < w; ++ww) wpre += wsum[ww];
    int excl = s_carry + wpre + sc - s;
#pragma unroll
    for (int i = 0; i < 4; ++i) {
      if (n0 + i < N) { dptr[n0 + i] = excl; cursor[n0 + i] = excl; }
      excl += v[i];
    }
    __syncthreads();
    if (tid == 255) s_carry += wsum[0] + wsum[1] + wsum[2] + wsum[3];
    __syncthreads();
  }
  if (threadIdx.x == 0) dptr[N] = s_carry;
}

// ---------------- scatter: dst-sorted edge permutation + permuted src/dst --------------
__global__ void k_fill(const int* __restrict__ dst, const int* __restrict__ src,
                       int* __restrict__ cursor, int* __restrict__ perm,
                       int* __restrict__ srcP, int* __restrict__ dstP, int E) {
  int e = blockIdx.x * blockDim.x + threadIdx.x;
  if (e < E) {
    int d = dst[e];
    int slot = atomicAdd(&cursor[d], 1);
    perm[slot] = e;
    srcP[slot] = src[e];
    dstP[slot] = d;
  }
}

// ---------------- materialize h_l = relu(bn(hn_{l-1})) + h_{l-1} (fp32 + f16) ---------
__global__ __launch_bounds__(256) void k_hmat(
    const float* __restrict__ hn, const float* __restrict__ hp,
    const float* __restrict__ slab, const float* __restrict__ gm,
    const float* __restrict__ bt, float* __restrict__ hout,
    _Float16* __restrict__ hh, int N) {
  __shared__ float stats[128];
  const int tid = threadIdx.x;
  if (tid < 128) {
    float s = 0.f;
#pragma unroll
    for (int sl = 0; sl < NSLAB; ++sl) s += slab[sl * 128 + tid];
    stats[tid] = s;
  }
  __syncthreads();
  int idx = blockIdx.x * 256 + tid;
  if (idx >= N * 64) return;
  int o = idx & 63;
  float invN = 1.0f / (float)N;
  float mu = stats[o] * invN;
  float var = stats[64 + o] * invN - mu * mu;
  float rs = rsqrtf(var + BN_EPS) * gm[o];
  float v = fmaxf((hn[idx] - mu) * rs + bt[o], 0.f) + hp[idx];
  hout[idx] = v;
  hh[idx] = (_Float16)v;
}

// ---------------- FUSED NNConv message (MFMA) + per-node aggregation (R16-proven) ------
__global__ __launch_bounds__(512, 8) void k_msgagg(
    const float* __restrict__ ea, const int* __restrict__ perm,
    const float* __restrict__ eW1l, const float* __restrict__ eb1l,
    const _Float16* __restrict__ hh, const int* __restrict__ srcP,
    const int* __restrict__ dstP, const int* __restrict__ dptr,
    const _Float16* __restrict__ w2P, float* __restrict__ agg, int E, int N) {
  __shared__ _Float16 e1t[65][64];  // f16; k=64 is bias slice
  __shared__ float tileH[64][66];   // full-K message tile
  __shared__ float eat[64][ED];
  __shared__ float w1s[ED * 64];
  __shared__ float b1s[64];

  const int tid = threadIdx.x;
  const int wid = tid >> 6, l = tid & 63;
  const int mh = wid >> 2, quad = wid & 3;   // wave = (m-half, feature-quad)
  const int lo = l & 15, lg = l >> 4;
  const int e0 = blockIdx.x * 64;

  // ---- A-frags FIRST (2 m-groups/wave): latency hides under staging + e1 MLP ----
  half8 hsf[2][2];
#pragma unroll
  for (int mm = 0; mm < 2; ++mm) {
    int s = e0 + (mh * 2 + mm) * 16 + lo;
    if (s < E) {
      const _Float16* hr = hh + (size_t)srcP[s] * 64;
      hsf[mm][0] = *(const half8*)(hr + lg * 8);
      hsf[mm][1] = *(const half8*)(hr + 32 + lg * 8);
    } else {
      half8 z = {0, 0, 0, 0, 0, 0, 0, 0};
      hsf[mm][0] = z;
      hsf[mm][1] = z;
    }
  }

  // ---- stage w1/b1 + ea gather ----
  if (tid < ED * 64) w1s[tid] = eW1l[tid];
  else if (tid < ED * 64 + 64) b1s[tid - ED * 64] = eb1l[tid - ED * 64];
  if (tid >= 448) {
    int s = e0 + (tid - 448);
    if (s < E) {
      int e = perm[s];
#pragma unroll
      for (int i = 0; i < ED; ++i) eat[tid - 448][i] = ea[(size_t)e * ED + i];
    } else {
#pragma unroll
      for (int i = 0; i < ED; ++i) eat[tid - 448][i] = 0.f;
    }
  }
  __syncthreads();

  // ---- edge MLP layer1 into LDS: e1t[k][edge] (f16) ----
  for (int idx = tid; idx < 65 * 64; idx += 512) {
    int el = idx & 63, k = idx >> 6;
    float v = 1.0f;  // bias slice k=64
    if (k < 64) {
      v = b1s[k];
#pragma unroll
      for (int i = 0; i < ED; ++i) v = fmaf(eat[el][i], w1s[i * 64 + k], v);
      v = fmaxf(v, 0.f);
    }
    e1t[k][el] = (_Float16)v;
  }
  __syncthreads();  // e1t ready

  // ---- K-loop: ALL 65 slices, 4-deep B prefetch ring, full-K accumulation ----
  f32x4 acc[2] = {};
  const half8* wp = (const half8*)w2P;  // [65][8][64] half8 units
  half8 Br[4][2];
#pragma unroll
  for (int d = 0; d < 4; ++d) {
    Br[d][0] = wp[((size_t)d * 8 + quad * 2 + 0) * 64 + l];
    Br[d][1] = wp[((size_t)d * 8 + quad * 2 + 1) * 64 + l];
  }
  const int mb0 = (mh * 2 + 0) * 16 + lo;
  const int mb1 = (mh * 2 + 1) * 16 + lo;
#pragma unroll 65
  for (int k = 0; k < 65; ++k) {
    const int d = k & 3;  // static under full unroll
    const _Float16 s0 = e1t[k][mb0];
    const _Float16 s1 = e1t[k][mb1];
    half8 A00 = hsf[0][0] * s0;
    half8 A01 = hsf[0][1] * s0;
    half8 A10 = hsf[1][0] * s1;
    half8 A11 = hsf[1][1] * s1;
    acc[0] = __builtin_amdgcn_mfma_f32_16x16x32_f16(A00, Br[d][0], acc[0], 0, 0, 0);
    acc[0] = __builtin_amdgcn_mfma_f32_16x16x32_f16(A01, Br[d][1], acc[0], 0, 0, 0);
    acc[1] = __builtin_amdgcn_mfma_f32_16x16x32_f16(A10, Br[d][0], acc[1], 0, 0, 0);
    acc[1] = __builtin_amdgcn_mfma_f32_16x16x32_f16(A11, Br[d][1], acc[1], 0, 0, 0);
    if (k + 4 < 65) {  // refill slot d, lands 4 iterations ahead
      Br[d][0] = wp[((size_t)(k + 4) * 8 + quad * 2 + 0) * 64 + l];
      Br[d][1] = wp[((size_t)(k + 4) * 8 + quad * 2 + 1) * 64 + l];
    }
  }

  // ---- store msg quadrant (full-K sums; D layout: col=l&15, row=(l>>4)*4+reg) ----
#pragma unroll
  for (int mm = 0; mm < 2; ++mm)
#pragma unroll
    for (int r = 0; r < 4; ++r)
      tileH[(mh * 2 + mm) * 16 + lg * 4 + r][quad * 16 + lo] = acc[mm][r];
  __syncthreads();

  // ---- per-node aggregation from LDS (plain store interior, atomic boundary) ----
  const int o = tid & 63, r8 = tid >> 6;
  const int lastSlot = (e0 + 63 < E) ? (e0 + 63) : (E - 1);
  int nLo = dstP[e0], nHi = dstP[lastSlot];
  nLo = (nLo < 0) ? 0 : ((nLo >= N) ? N - 1 : nLo);   // clamp: poisoned-replay safety
  nHi = (nHi < 0) ? 0 : ((nHi >= N) ? N - 1 : nHi);
  for (int nn = nLo + r8; nn <= nHi; nn += 8) {
    int d0 = dptr[nn], d1 = dptr[nn + 1];
    d0 = (d0 < 0) ? 0 : d0;
    d1 = (d1 > E) ? E : d1;
    int j0 = (d0 > e0) ? d0 : e0;
    int j1 = (d1 < e0 + 64) ? d1 : (e0 + 64);
    float sum = 0.f;
    for (int j = j0; j < j1; ++j) sum += tileH[j - e0][o];
    float* dp = agg + (size_t)nn * 64 + o;
    if (d0 < e0 || d1 > e0 + 64) { if (j1 > j0) atomicAdd(dp, sum); }
    else *dp = sum;
  }
}

// ---------------- update_l: hn_l = agg/deg + h_l@root + cbias ; stats_l; zero agg ------
__global__ __launch_bounds__(256) void k_update(
    const float* __restrict__ hcur, float* __restrict__ agg,
    const float* __restrict__ deg, const float* __restrict__ root,
    const float* __restrict__ cb, float* __restrict__ hn_out,
    float* __restrict__ slab_out, int N) {
  __shared__ float hrow[16][64];
  __shared__ float red[2][256];
  const int tid = threadIdx.x, o = tid & 63, r = tid >> 6;
  const int nb = blockIdx.x * 16;
#pragma unroll
  for (int ii = 0; ii < 4; ++ii) {
    int n = nb + ii * 4 + r;
    hrow[ii * 4 + r][o] = (n < N) ? hcur[(size_t)n * 64 + o] : 0.f;
  }
  __syncthreads();
  float acc[4] = {0.f, 0.f, 0.f, 0.f};
  for (int c = 0; c < 64; ++c) {
    float rv = root[c * 64 + o];
#pragma unroll
    for (int ii = 0; ii < 4; ++ii) acc[ii] = fmaf(hrow[ii * 4 + r][c], rv, acc[ii]);
  }
  float s = 0.f, ss = 0.f;
  const float cbv = cb[o];
#pragma unroll
  for (int ii = 0; ii < 4; ++ii) {
    int n = nb + ii * 4 + r;
    if (n < N) {
      float a = agg[(size_t)n * 64 + o];
      agg[(size_t)n * 64 + o] = 0.f;  // reset for next layer's atomics
      float v = acc[ii] + cbv + a / fmaxf(deg[n], 1.0f);
      hn_out[(size_t)n * 64 + o] = v;
      s += v;
      ss += v * v;
    }
  }
  red[0][tid] = s;
  red[1][tid] = ss;
  __syncthreads();
  if (r == 0) {
    float t0 = red[0][o] + red[0][64 + o] + red[0][128 + o] + red[0][192 + o];
    float t1 = red[1][o] + red[1][64 + o] + red[1][128 + o] + red[1][192 + o];
    float* sl = slab_out + (size_t)(blockIdx.x & (NSLAB - 1)) * 128;
    atomicAdd(&sl[o], t0);
    atomicAdd(&sl[64 + o], t1);
  }
}

// ---------------- fused Set2Set: LDS-staged attention, all steps + head ---------------
__global__ __launch_bounds__(256) void k_s2s_all(
    const float* __restrict__ hn2, const float* __restrict__ h2,
    const float* __restrict__ slab2, const float* __restrict__ gm,
    const float* __restrict__ bt, const int* __restrict__ ptr,
    const float* __restrict__ WihT, const float* __restrict__ WhhT,
    const float* __restrict__ gbias,
    const float* __restrict__ hW1, const float* __restrict__ hb1,
    const float* __restrict__ hW2, const float* __restrict__ hb2,
    const float* __restrict__ hW3, const float* __restrict__ hb3,
    float* __restrict__ out, int N) {
  __shared__ float hvs[CAP * 65];   // staged node features (pad 65 -> conflict-free)
  __shared__ float stats[128];
  __shared__ float mu_s[64], rs_s[64], bt_s[64];
  __shared__ float qs[128];
  __shared__ float hlc[64], clc[64];
  __shared__ float gates[256];
  __shared__ float qv[64];
  __shared__ float ev[256];
  __shared__ float av[CAP];
  __shared__ float redM[4], redS[4];
  __shared__ float redR[4][64];
  __shared__ float z1[64], z2[32];
  const int b = blockIdx.x, tid = threadIdx.x;
  const int wid = tid >> 6, lane = tid & 63;

  if (tid < 128) {
    float s = 0.f;
#pragma unroll
    for (int sl = 0; sl < NSLAB; ++sl) s += slab2[sl * 128 + tid];
    stats[tid] = s;
    qs[tid] = 0.f;
  }
  if (tid < 64) { hlc[tid] = 0.f; clc[tid] = 0.f; }
  __syncthreads();
  if (tid < 64) {
    float invN = 1.0f / (float)N;
    float mu = stats[tid] * invN;
    float var = stats[64 + tid] * invN - mu * mu;
    mu_s[tid] = mu;
    rs_s[tid] = rsqrtf(var + BN_EPS) * gm[tid];
    bt_s[tid] = bt[tid];
  }
  __syncthreads();
  int beg = ptr[b], end = ptr[b + 1];
  if (beg < 0) beg = 0;              // poisoned-replay safety
  if (end > N) end = N;
  const int nn = (end > beg) ? (end - beg) : 0;
  const bool big = nn > CAP;

  if (!big) {  // stage hv once: h3[n] = relu(bn(hn2)) + h2, reused across all steps
    for (int idx = tid; idx < nn * 64; idx += 256) {
      int n = idx >> 6, o = idx & 63;
      size_t g = (size_t)(beg + n) * 64 + o;
      hvs[n * 65 + o] = fmaxf((hn2[g] - mu_s[o]) * rs_s[o] + bt_s[o], 0.f) + h2[g];
    }
  }
  __syncthreads();

  for (int step = 0; step < NSTEPS; ++step) {
    // ---- LSTM ----
    float g = gbias[tid];
    for (int i = 0; i < 128; ++i) g = fmaf(qs[i], WihT[i * 256 + tid], g);
    for (int i = 0; i < 64; ++i) g = fmaf(hlc[i], WhhT[i * 256 + tid], g);
    gates[tid] = g;
    __syncthreads();
    if (tid < 64) {
      float ig = sigm(gates[tid]);
      float fg = sigm(gates[64 + tid]);
      float gg = tanhf(gates[128 + tid]);
      float og = sigm(gates[192 + tid]);
      float c = fg * clc[tid] + ig * gg;
      clc[tid] = c;
      float hnew = og * tanhf(c);
      hlc[tid] = hnew;
      qv[tid] = hnew;
    }
    __syncthreads();

    if (!big) {
      // ---- lane-per-node attention from LDS ----
      if (tid < nn) {
        float s = 0.f;
#pragma unroll 8
        for (int o = 0; o < 64; ++o) s = fmaf(hvs[tid * 65 + o], qv[o], s);
        ev[tid] = s;
      } else {
        ev[tid] = -INFINITY;
      }
      __syncthreads();
      if (tid < 64) {
        float m4 = fmaxf(fmaxf(ev[tid], ev[64 + tid]), fmaxf(ev[128 + tid], ev[192 + tid]));
#pragma unroll
        for (int s = 32; s; s >>= 1) m4 = fmaxf(m4, __shfl_xor(m4, s));
        if (tid == 0) redM[0] = m4;
      }
      __syncthreads();
      const float m = redM[0];
      float a = 0.f;
      if (tid < nn) { a = expf(ev[tid] - m); av[tid] = a; }
      __syncthreads();          // av writes done before reuse of ev
      ev[tid] = a;
      __syncthreads();
      if (tid < 64) {
        float s4 = ev[tid] + ev[64 + tid] + ev[128 + tid] + ev[192 + tid];
#pragma unroll
        for (int s = 32; s; s >>= 1) s4 += __shfl_xor(s4, s);
        if (tid == 0) redS[0] = s4;
      }
      __syncthreads();
      const float sden = redS[0];
      if (tid < 128) {
        if (tid < 64) {
          qs[tid] = qv[tid];
        } else {
          int o = tid - 64;
          float r = 0.f;
          for (int n = 0; n < nn; ++n) r = fmaf(av[n], hvs[n * 65 + o], r);
          qs[tid] = (nn > 0) ? r / sden : 0.f;
        }
      }
      __syncthreads();
    } else {
      // ---- fallback: global-read path (graphs > CAP nodes; never hit in practice) ----
      const float q = qv[lane];
      float mw = -INFINITY;
      for (int n = beg + wid; n < end; n += 4) {
        float hv = fmaxf((hn2[(size_t)n * 64 + lane] - mu_s[lane]) * rs_s[lane] + bt_s[lane],
                         0.f) + h2[(size_t)n * 64 + lane];
        float p = hv * q;
#pragma unroll
        for (int s = 32; s; s >>= 1) p += __shfl_xor(p, s);
        mw = fmaxf(mw, p);
      }
      if (lane == 0) redM[wid] = mw;
      __syncthreads();
      const float m = fmaxf(fmaxf(redM[0], redM[1]), fmaxf(redM[2], redM[3]));
      float ssum = 0.f, racc = 0.f;
      for (int n = beg + wid; n < end; n += 4) {
        float hv = fmaxf((hn2[(size_t)n * 64 + lane] - mu_s[lane]) * rs_s[lane] + bt_s[lane],
                         0.f) + h2[(size_t)n * 64 + lane];
        float p = hv * q;
#pragma unroll
        for (int s = 32; s; s >>= 1) p += __shfl_xor(p, s);
        float a = expf(p - m);
        ssum += a;
        racc = fmaf(a, hv, racc);
      }
      if (lane == 0) redS[wid] = ssum;
      redR[wid][lane] = racc;
      __syncthreads();
      if (tid < 128) {
        if (tid < 64) {
          qs[tid] = qv[tid];
        } else {
          int o2 = tid - 64;
          float rsum = redR[0][o2] + redR[1][o2] + redR[2][o2] + redR[3][o2];
          float sd = redS[0] + redS[1] + redS[2] + redS[3];
          qs[tid] = (end > beg) ? rsum / sd : 0.0f;
        }
      }
      __syncthreads();
    }
  }

  // ---- regression head (reads final q_star in qs) ----
  if (tid < 64) {
    float a = hb1[tid];
    for (int i = 0; i < 128; ++i) a = fmaf(qs[i], hW1[i * 64 + tid], a);
    z1[tid] = fmaxf(a, 0.0f);
  }
  __syncthreads();
  if (tid < 32) {
    float a2 = hb2[tid];
    for (int i = 0; i < 64; ++i) a2 = fmaf(z1[i], hW2[i * 32 + tid], a2);
    z2[tid] = fmaxf(a2, 0.0f);
  }
  __syncthreads();
  if (tid < 64) {
    float p = (tid < 32) ? z2[tid] * hW3[tid] : 0.0f;
#pragma unroll
    for (int s = 32; s; s >>= 1) p += __shfl_xor(p, s);
    if (tid == 0) out[b] = p + hb3[0];
  }
}

extern "C" void kernel_launch(void* const* d_in, const int* in_sizes, int n_in,
                              void* d_out, int out_size, void* d_ws, size_t ws_size,
                              hipStream_t stream) {
  const float* x = (const float*)d_in[0];
  const int* eidx = (const int*)d_in[1];
  const float* ea = (const float*)d_in[2];
  const int* batch = (const int*)d_in[3];
  const float* Wenc = (const float*)d_in[4];
  const float* benc = (const float*)d_in[5];
  const float* eW1 = (const float*)d_in[6];
  const float* eb1 = (const float*)d_in[7];
  const float* eW2 = (const float*)d_in[8];
  const float* eb2 = (const float*)d_in[9];
  const float* root = (const float*)d_in[10];
  const float* cbias = (const float*)d_in[11];
  const float* gamma = (const float*)d_in[12];
  const float* beta = (const float*)d_in[13];
  const float* Wih = (const float*)d_in[14];
  const float* Whh = (const float*)d_in[15];
  const float* bih = (const float*)d_in[16];
  const float* bhh = (const float*)d_in[17];
  const float* hW1 = (const float*)d_in[18];
  const float* hb1 = (const float*)d_in[19];
  const float* hW2 = (const float*)d_in[20];
  const float* hb2 = (const float*)d_in[21];
  const float* hW3 = (const float*)d_in[22];
  const float* hb3 = (const float*)d_in[23];

  const int N = in_sizes[0] / ND;
  const int E = in_sizes[1] / 2;
  const int B = out_size;
  const int* srcp = eidx;
  const int* dstp = eidx + E;
  const int Etiles = (E + 63) / 64;

  // ---- workspace layout: deg | [zeroed: agg|bnslab] | rest ----
  float* ws = (float*)d_ws;
  float* deg = ws;                                     // N (zeroed by k_zdeg)
  float* agg = deg + N;                                // N*64
  float* bnslab = agg + (size_t)N * 64;                // NL * NSLAB * 128
  const long NZ = (long)((size_t)N * 64 + NL * NSLAB * 128);
  float* h0 = bnslab + NL * NSLAB * 128;               // N*64
  float* h1 = h0 + (size_t)N * 64;                     // N*64
  float* h2 = h1 + (size_t)N * 64;                     // N*64
  float* hn0 = h2 + (size_t)N * 64;                    // N*64
  float* hn1 = hn0 + (size_t)N * 64;                   // N*64
  float* hn2 = hn1 + (size_t)N * 64;                   // N*64
  _Float16* w2P = (_Float16*)(hn2 + (size_t)N * 64);   // 3 * 65*8*64*8 f16
  _Float16* hhalf = w2P + (size_t)3 * 65 * 8 * 64 * 8; // N*64 f16
  float* WihT = (float*)(hhalf + (size_t)N * 64);      // 128*256
  float* WhhT = WihT + 128 * 256;                      // 64*256
  float* gbias = WhhT + 64 * 256;                      // 256
  int* dptr = (int*)(gbias + 256);                     // N+1
  int* cursor = dptr + N + 1;                          // N
  int* perm = cursor + N;                              // E
  int* srcP = perm + E;                                // E
  int* dstP = srcP + E;                                // E
  int* ptr = dstP + E;                                 // B+1

  const int nbEnc = (N * 64 + 255) / 256;
  const int nbDeg = (E + 255) / 256;
  const int nbPtr = (N + 255) / 256;
  const int nbPackW = (192 * 256 + 256 + 255) / 256;
  const int nbPack3 = 130 * NL;
  const int nbZero = (int)((NZ / 4 + 255) / 256);

  k_zdeg<<<(N + 255) / 256, 256, 0, stream>>>(deg, N);
  k_setup<<<nbEnc + nbDeg + nbPtr + nbPackW + nbPack3 + nbZero, 256, 0, stream>>>(
      x, Wenc, benc, h0, hhalf, N, dstp, deg, E, batch, ptr, B,
      Wih, Whh, bih, bhh, WihT, WhhT, gbias, eW2, eb2, w2P, agg, NZ,
      nbEnc, nbDeg, nbPtr, nbPackW, nbPack3);
  k_scan<<<1, 256, 0, stream>>>(deg, dptr, cursor, N);
  k_fill<<<(E + 255) / 256, 256, 0, stream>>>(dstp, srcp, cursor, perm, srcP, dstP, E);

  float* hbuf[3] = {h0, h1, h2};
  float* hnbuf[3] = {hn0, hn1, hn2};
  for (int l = 0; l < NL; ++l) {
    float* slab_l = bnslab + (size_t)l * NSLAB * 128;
    const _Float16* w2_l = w2P + (size_t)l * 65 * 8 * 64 * 8;
    if (l > 0) {
      k_hmat<<<(N * 64 + 255) / 256, 256, 0, stream>>>(
          hnbuf[l - 1], hbuf[l - 1], bnslab + (size_t)(l - 1) * NSLAB * 128,
          gamma + (l - 1) * 64, beta + (l - 1) * 64, hbuf[l], hhalf, N);
    }
    k_msgagg<<<Etiles, 512, 0, stream>>>(ea, perm, eW1 + (size_t)l * ED * 64,
                                         eb1 + (size_t)l * 64, hhalf, srcP, dstP, dptr,
                                         w2_l, agg, E, N);
    k_update<<<(N + 15) / 16, 256, 0, stream>>>(hbuf[l], agg, deg,
                                                root + (size_t)l * 64 * 64,
                                                cbias + l * 64, hnbuf[l], slab_l, N);
  }

  k_s2s_all<<<B, 256, 0, stream>>>(hn2, h2, bnslab + (size_t)2 * NSLAB * 128,
                                   gamma + 2 * 64, beta + 2 * 64, ptr, WihT, WhhT, gbias,
                                   hW1, hb1, hW2, hb2, hW3, hb3, (float*)d_out, N);
}

// Round 20
// 181.422 us; speedup vs baseline: 1.2559x; 1.0138x over previous
//
#include <hip/hip_runtime.h>
#include <math.h>

#define ND 11      // node feature dim
#define ED 5       // edge feature dim
#define NL 3       // NNConv layers
#define NSTEPS 3   // Set2Set steps
#define BN_EPS 1e-5f
#define NSLAB 32   // bn-stat slabs (spread same-address atomics)
#define CAP 256    // max LDS-staged nodes per graph in s2s (CAP=64 regressed 2.6x, R18)

typedef _Float16 half8 __attribute__((ext_vector_type(8)));
typedef float f32x4 __attribute__((ext_vector_type(4)));

__device__ __forceinline__ float sigm(float x) { return 1.0f / (1.0f + expf(-x)); }

// ---------------- fused setup: enc | deg | ptr | packW | pack3 | zero ----------------
__global__ __launch_bounds__(256) void k_setup(
    const float* __restrict__ x, const float* __restrict__ Wenc,
    const float* __restrict__ benc, float* __restrict__ h0,
    _Float16* __restrict__ hh, int N,
    const int* __restrict__ dst, float* __restrict__ deg, int E,
    const int* __restrict__ batch, int* __restrict__ ptr, int B,
    const float* __restrict__ Wih, const float* __restrict__ Whh,
    const float* __restrict__ bih, const float* __restrict__ bhh,
    float* __restrict__ WihT, float* __restrict__ WhhT, float* __restrict__ gbias,
    const float* __restrict__ w2, const float* __restrict__ b2,
    _Float16* __restrict__ w2P, float* __restrict__ zp, long NZ,
    int nbEnc, int nbDeg, int nbPtr, int nbPackW, int nbPack3) {
  int bid = blockIdx.x;
  const int tid = threadIdx.x;
  if (bid < nbEnc) {  // node encoder: h0 = relu(x @ W_enc + b); also f16 copy
    int idx = bid * 256 + tid;
    if (idx < N * 64) {
      int n = idx >> 6, j = idx & 63;
      float acc = benc[j];
#pragma unroll
      for (int i = 0; i < ND; ++i) acc = fmaf(x[n * ND + i], Wenc[i * 64 + j], acc);
      float v = fmaxf(acc, 0.0f);
      h0[idx] = v;
      hh[idx] = (_Float16)v;
    }
    return;
  }
  bid -= nbEnc;
  if (bid < nbDeg) {  // in-degree histogram (deg zeroed by k_zdeg, prior node)
    int e = bid * 256 + tid;
    if (e < E) atomicAdd(&deg[dst[e]], 1.0f);
    return;
  }
  bid -= nbDeg;
  if (bid < nbPtr) {  // graph row pointers from sorted batch
    int n = bid * 256 + tid;
    if (n < N) {
      int b = batch[n];
      int pb = (n == 0) ? -1 : batch[n - 1];
      for (int g = pb + 1; g <= b; ++g) ptr[g] = n;
      if (n == N - 1)
        for (int g = b + 1; g <= B; ++g) ptr[g] = N;
    }
    return;
  }
  bid -= nbPtr;
  if (bid < nbPackW) {  // transpose LSTM weights
    int idx = bid * 256 + tid;
    if (idx < 128 * 256) {
      int i = idx >> 8, g = idx & 255;
      WihT[i * 256 + g] = Wih[g * 128 + i];
    } else if (idx < 192 * 256) {
      int j = idx - 128 * 256;
      int i = j >> 8, g = j & 255;
      WhhT[i * 256 + g] = Whh[g * 64 + i];
    } else if (idx < 192 * 256 + 256) {
      int g = idx - 192 * 256;
      gbias[g] = bih[g] + bhh[g];
    }
    return;
  }
  bid -= nbPackW;
  if (bid < nbPack3) {  // pack eW2 (+eb2 as slice 64) into MFMA-B frag layout
    int lay = bid / 130;
    int idx = (bid % 130) * 256 + tid;  // < 65*8*64 = 33280 exactly
    int l = idx & 63;
    int f = (idx >> 6) & 7;
    int s = idx >> 9;
    int nf = f >> 1, kf = f & 1;
    const float* srow = (s < 64) ? (w2 + (size_t)lay * 64 * 4096 + (size_t)s * 4096)
                                 : (b2 + (size_t)lay * 4096);
    int o = nf * 16 + (l & 15);
    int hb = kf * 32 + (l >> 4) * 8;
    half8 v;
#pragma unroll
    for (int j = 0; j < 8; ++j) v[j] = (_Float16)srow[(hb + j) * 64 + o];
    *(half8*)(w2P + ((size_t)lay * 65 * 8 * 64 + idx) * 8) = v;
    return;
  }
  bid -= nbPack3;
  {  // zero agg|bnslab region (deg excluded; zeroed by k_zdeg before this node)
    long i4 = ((long)bid * 256 + tid) * 4;
    if (i4 + 3 < NZ) *(float4*)(zp + i4) = make_float4(0.f, 0.f, 0.f, 0.f);
    else for (; i4 < NZ; ++i4) zp[i4] = 0.f;
  }
}

// deg must be zeroed BEFORE k_setup's histogram part -> separate tiny kernel, first node.
__global__ void k_zdeg(float* __restrict__ deg, int N) {
  int i = blockIdx.x * blockDim.x + threadIdx.x;
  if (i < N) deg[i] = 0.f;
}

// ---------------- single-block prefix scan of deg -> dptr / cursor (R4-R7 proven) ------
__global__ __launch_bounds__(256) void k_scan(const float* __restrict__ deg,
                                              int* __restrict__ dptr,
                                              int* __restrict__ cursor, int N) {
  __shared__ int wsum[4];
  __shared__ int s_carry;
  const int tid = threadIdx.x, lane = tid & 63, w = tid >> 6;
  if (tid == 0) s_carry = 0;
  __syncthreads();
  for (int base = 0; base < N; base += 1024) {
    int n0 = base + tid * 4;
    int v[4];
    int s = 0;
#pragma unroll
    for (int i = 0; i < 4; ++i) { v[i] = (n0 + i < N) ? (int)deg[n0 + i] : 0; s += v[i]; }
    int sc = s;  // inclusive wave scan
#pragma unroll
    for (int off = 1; off < 64; off <<= 1) {
      int t = __shfl_up(sc, off);
      if (lane >= off) sc += t;
    }
    if (lane == 63) wsum[w] = sc;
    __syncthreads();
    int wpre = 0;
    for (int ww = 0; ww < w; ++ww) wpre += wsum[ww];
    int excl = s_carry + wpre + sc - s;
#pragma unroll
    for (int i = 0; i < 4; ++i) {
      if (n0 + i < N) { dptr[n0 + i] = excl; cursor[n0 + i] = excl; }
      excl += v[i];
    }
    __syncthreads();
    if (tid == 255) s_carry += wsum[0] + wsum[1] + wsum[2] + wsum[3];
    __syncthreads();
  }
  if (threadIdx.x == 0) dptr[N] = s_carry;
}

// ---------------- scatter: dst-sorted edge permutation + permuted src/dst --------------
__global__ void k_fill(const int* __restrict__ dst, const int* __restrict__ src,
                       int* __restrict__ cursor, int* __restrict__ perm,
                       int* __restrict__ srcP, int* __restrict__ dstP, int E) {
  int e = blockIdx.x * blockDim.x + threadIdx.x;
  if (e < E) {
    int d = dst[e];
    int slot = atomicAdd(&cursor[d], 1);
    perm[slot] = e;
    srcP[slot] = src[e];
    dstP[slot] = d;
  }
}

// ---------------- materialize h_l = relu(bn(hn_{l-1})) + h_{l-1} (fp32 + f16) ---------
__global__ __launch_bounds__(256) void k_hmat(
    const float* __restrict__ hn, const float* __restrict__ hp,
    const float* __restrict__ slab, const float* __restrict__ gm,
    const float* __restrict__ bt, float* __restrict__ hout,
    _Float16* __restrict__ hh, int N) {
  __shared__ float stats[128];
  const int tid = threadIdx.x;
  if (tid < 128) {
    float s = 0.f;
#pragma unroll
    for (int sl = 0; sl < NSLAB; ++sl) s += slab[sl * 128 + tid];
    stats[tid] = s;
  }
  __syncthreads();
  int idx = blockIdx.x * 256 + tid;
  if (idx >= N * 64) return;
  int o = idx & 63;
  float invN = 1.0f / (float)N;
  float mu = stats[o] * invN;
  float var = stats[64 + o] * invN - mu * mu;
  float rs = rsqrtf(var + BN_EPS) * gm[o];
  float v = fmaxf((hn[idx] - mu) * rs + bt[o], 0.f) + hp[idx];
  hout[idx] = v;
  hh[idx] = (_Float16)v;
}

// ---------------- FUSED NNConv message (MFMA) + per-node aggregation -------------------
// Wave = (k-half, feature-quad): ZERO B-stream duplication across the 8 waves (528KB
// unique L2 reads/block vs 1.04MB issued in the (mh,quad) mapping). Register budget
// trimmed: 2-deep Br ring, e1 scales from LDS -> ~64 data VGPRs; bounds (512,4) caps 128.
__global__ __launch_bounds__(512, 4) void k_msgagg(
    const float* __restrict__ ea, const int* __restrict__ perm,
    const float* __restrict__ eW1l, const float* __restrict__ eb1l,
    const _Float16* __restrict__ hh, const int* __restrict__ srcP,
    const int* __restrict__ dstP, const int* __restrict__ dptr,
    const _Float16* __restrict__ w2P, float* __restrict__ agg, int E, int N) {
  __shared__ _Float16 e1t[65][64];   // f16; k=64 is bias slice
  __shared__ float tileH[2][64][66]; // per-k-half partial message tiles
  __shared__ float eat[64][ED];
  __shared__ float w1s[ED * 64];
  __shared__ float b1s[64];

  const int tid = threadIdx.x;
  const int wid = tid >> 6, l = tid & 63;
  const int half = wid >> 2, quad = wid & 3;  // wave = (k-half, feature-quad)
  const int lo = l & 15, lg = l >> 4;
  const int e0 = blockIdx.x * 64;

  // ---- A-frags FIRST (all 4 m-groups): latency hides under staging + e1 MLP ----
  half8 hsf[4][2];
#pragma unroll
  for (int m = 0; m < 4; ++m) {
    int s = e0 + m * 16 + lo;
    if (s < E) {
      const _Float16* hr = hh + (size_t)srcP[s] * 64;
      hsf[m][0] = *(const half8*)(hr + lg * 8);
      hsf[m][1] = *(const half8*)(hr + 32 + lg * 8);
    } else {
      half8 z = {0, 0, 0, 0, 0, 0, 0, 0};
      hsf[m][0] = z;
      hsf[m][1] = z;
    }
  }

  // ---- stage w1/b1 + ea gather ----
  if (tid < ED * 64) w1s[tid] = eW1l[tid];
  else if (tid < ED * 64 + 64) b1s[tid - ED * 64] = eb1l[tid - ED * 64];
  if (tid >= 448) {
    int s = e0 + (tid - 448);
    if (s < E) {
      int e = perm[s];
#pragma unroll
      for (int i = 0; i < ED; ++i) eat[tid - 448][i] = ea[(size_t)e * ED + i];
    } else {
#pragma unroll
      for (int i = 0; i < ED; ++i) eat[tid - 448][i] = 0.f;
    }
  }
  __syncthreads();

  // ---- edge MLP layer1 into LDS: e1t[k][edge] (f16) ----
  for (int idx = tid; idx < 65 * 64; idx += 512) {
    int el = idx & 63, k = idx >> 6;
    float v = 1.0f;  // bias slice k=64
    if (k < 64) {
      v = b1s[k];
#pragma unroll
      for (int i = 0; i < ED; ++i) v = fmaf(eat[el][i], w1s[i * 64 + k], v);
      v = fmaxf(v, 0.f);
    }
    e1t[k][el] = (_Float16)v;
  }
  __syncthreads();  // e1t ready

  // ---- K-loop: 33 slices for this half (half1 zeroes its first, shared, slice) ----
  const int kb = half ? 32 : 0;
  f32x4 acc[4] = {};
  const half8* wp = (const half8*)w2P;  // [65][8][64] half8 units
  half8 Br[2][2];                       // 2-deep B prefetch ring (register slim)
#pragma unroll
  for (int d = 0; d < 2; ++d) {
    Br[d][0] = wp[((size_t)(kb + d) * 8 + quad * 2 + 0) * 64 + l];
    Br[d][1] = wp[((size_t)(kb + d) * 8 + quad * 2 + 1) * 64 + l];
  }
#pragma unroll 33
  for (int i = 0; i < 33; ++i) {
    const int d = i & 1;  // static under full unroll
    const int k = kb + i;
    const bool zslice = (half && i == 0);  // k=32 owned by half0
#pragma unroll
    for (int m = 0; m < 4; ++m) {
      const _Float16 s16 = zslice ? (_Float16)0.f : e1t[k][m * 16 + lo];
      half8 A0 = hsf[m][0] * s16;
      half8 A1 = hsf[m][1] * s16;
      acc[m] = __builtin_amdgcn_mfma_f32_16x16x32_f16(A0, Br[d][0], acc[m], 0, 0, 0);
      acc[m] = __builtin_amdgcn_mfma_f32_16x16x32_f16(A1, Br[d][1], acc[m], 0, 0, 0);
    }
    if (i + 2 < 33) {  // refill slot d, lands 2 iterations ahead
      Br[d][0] = wp[((size_t)(kb + i + 2) * 8 + quad * 2 + 0) * 64 + l];
      Br[d][1] = wp[((size_t)(kb + i + 2) * 8 + quad * 2 + 1) * 64 + l];
    }
  }

  // ---- store msg quadrant (D layout: col=l&15, row=(l>>4)*4+reg) ----
#pragma unroll
  for (int m = 0; m < 4; ++m)
#pragma unroll
    for (int r = 0; r < 4; ++r)
      tileH[half][m * 16 + lg * 4 + r][quad * 16 + lo] = acc[m][r];
  __syncthreads();

  // ---- per-node aggregation from LDS (plain store interior, atomic boundary) ----
  const int o = tid & 63, r8 = tid >> 6;
  const int lastSlot = (e0 + 63 < E) ? (e0 + 63) : (E - 1);
  int nLo = dstP[e0], nHi = dstP[lastSlot];
  nLo = (nLo < 0) ? 0 : ((nLo >= N) ? N - 1 : nLo);   // clamp: poisoned-replay safety
  nHi = (nHi < 0) ? 0 : ((nHi >= N) ? N - 1 : nHi);
  for (int nn = nLo + r8; nn <= nHi; nn += 8) {
    int d0 = dptr[nn], d1 = dptr[nn + 1];
    d0 = (d0 < 0) ? 0 : d0;
    d1 = (d1 > E) ? E : d1;
    int j0 = (d0 > e0) ? d0 : e0;
    int j1 = (d1 < e0 + 64) ? d1 : (e0 + 64);
    float sum = 0.f;
    for (int j = j0; j < j1; ++j) sum += tileH[0][j - e0][o] + tileH[1][j - e0][o];
    float* dp = agg + (size_t)nn * 64 + o;
    if (d0 < e0 || d1 > e0 + 64) { if (j1 > j0) atomicAdd(dp, sum); }
    else *dp = sum;
  }
}

// ---------------- update_l: hn_l = agg/deg + h_l@root + cbias ; stats_l; zero agg ------
__global__ __launch_bounds__(256) void k_update(
    const float* __restrict__ hcur, float* __restrict__ agg,
    const float* __restrict__ deg, const float* __restrict__ root,
    const float* __restrict__ cb, float* __restrict__ hn_out,
    float* __restrict__ slab_out, int N) {
  __shared__ float hrow[16][64];
  __shared__ float red[2][256];
  const int tid = threadIdx.x, o = tid & 63, r = tid >> 6;
  const int nb = blockIdx.x * 16;
#pragma unroll
  for (int ii = 0; ii < 4; ++ii) {
    int n = nb + ii * 4 + r;
    hrow[ii * 4 + r][o] = (n < N) ? hcur[(size_t)n * 64 + o] : 0.f;
  }
  __syncthreads();
  float acc[4] = {0.f, 0.f, 0.f, 0.f};
  for (int c = 0; c < 64; ++c) {
    float rv = root[c * 64 + o];
#pragma unroll
    for (int ii = 0; ii < 4; ++ii) acc[ii] = fmaf(hrow[ii * 4 + r][c], rv, acc[ii]);
  }
  float s = 0.f, ss = 0.f;
  const float cbv = cb[o];
#pragma unroll
  for (int ii = 0; ii < 4; ++ii) {
    int n = nb + ii * 4 + r;
    if (n < N) {
      float a = agg[(size_t)n * 64 + o];
      agg[(size_t)n * 64 + o] = 0.f;  // reset for next layer's atomics
      float v = acc[ii] + cbv + a / fmaxf(deg[n], 1.0f);
      hn_out[(size_t)n * 64 + o] = v;
      s += v;
      ss += v * v;
    }
  }
  red[0][tid] = s;
  red[1][tid] = ss;
  __syncthreads();
  if (r == 0) {
    float t0 = red[0][o] + red[0][64 + o] + red[0][128 + o] + red[0][192 + o];
    float t1 = red[1][o] + red[1][64 + o] + red[1][128 + o] + red[1][192 + o];
    float* sl = slab_out + (size_t)(blockIdx.x & (NSLAB - 1)) * 128;
    atomicAdd(&sl[o], t0);
    atomicAdd(&sl[64 + o], t1);
  }
}

// ---------------- fused Set2Set: LDS-staged attention, all steps + head ---------------
__global__ __launch_bounds__(256) void k_s2s_all(
    const float* __restrict__ hn2, const float* __restrict__ h2,
    const float* __restrict__ slab2, const float* __restrict__ gm,
    const float* __restrict__ bt, const int* __restrict__ ptr,
    const float* __restrict__ WihT, const float* __restrict__ WhhT,
    const float* __restrict__ gbias,
    const float* __restrict__ hW1, const float* __restrict__ hb1,
    const float* __restrict__ hW2, const float* __restrict__ hb2,
    const float* __restrict__ hW3, const float* __restrict__ hb3,
    float* __restrict__ out, int N) {
  __shared__ float hvs[CAP * 65];   // staged node features (pad 65 -> conflict-free)
  __shared__ float stats[128];
  __shared__ float mu_s[64], rs_s[64], bt_s[64];
  __shared__ float qs[128];
  __shared__ float hlc[64], clc[64];
  __shared__ float gates[256];
  __shared__ float qv[64];
  __shared__ float ev[256];
  __shared__ float av[CAP];
  __shared__ float redM[4], redS[4];
  __shared__ float redR[4][64];
  __shared__ float z1[64], z2[32];
  const int b = blockIdx.x, tid = threadIdx.x;
  const int wid = tid >> 6, lane = tid & 63;

  if (tid < 128) {
    float s = 0.f;
#pragma unroll
    for (int sl = 0; sl < NSLAB; ++sl) s += slab2[sl * 128 + tid];
    stats[tid] = s;
    qs[tid] = 0.f;
  }
  if (tid < 64) { hlc[tid] = 0.f; clc[tid] = 0.f; }
  __syncthreads();
  if (tid < 64) {
    float invN = 1.0f / (float)N;
    float mu = stats[tid] * invN;
    float var = stats[64 + tid] * invN - mu * mu;
    mu_s[tid] = mu;
    rs_s[tid] = rsqrtf(var + BN_EPS) * gm[tid];
    bt_s[tid] = bt[tid];
  }
  __syncthreads();
  int beg = ptr[b], end = ptr[b + 1];
  if (beg < 0) beg = 0;              // poisoned-replay safety
  if (end > N) end = N;
  const int nn = (end > beg) ? (end - beg) : 0;
  const bool big = nn > CAP;

  if (!big) {  // stage hv once: h3[n] = relu(bn(hn2)) + h2, reused across all steps
    for (int idx = tid; idx < nn * 64; idx += 256) {
      int n = idx >> 6, o = idx & 63;
      size_t g = (size_t)(beg + n) * 64 + o;
      hvs[n * 65 + o] = fmaxf((hn2[g] - mu_s[o]) * rs_s[o] + bt_s[o], 0.f) + h2[g];
    }
  }
  __syncthreads();

  for (int step = 0; step < NSTEPS; ++step) {
    // ---- LSTM ----
    float g = gbias[tid];
    for (int i = 0; i < 128; ++i) g = fmaf(qs[i], WihT[i * 256 + tid], g);
    for (int i = 0; i < 64; ++i) g = fmaf(hlc[i], WhhT[i * 256 + tid], g);
    gates[tid] = g;
    __syncthreads();
    if (tid < 64) {
      float ig = sigm(gates[tid]);
      float fg = sigm(gates[64 + tid]);
      float gg = tanhf(gates[128 + tid]);
      float og = sigm(gates[192 + tid]);
      float c = fg * clc[tid] + ig * gg;
      clc[tid] = c;
      float hnew = og * tanhf(c);
      hlc[tid] = hnew;
      qv[tid] = hnew;
    }
    __syncthreads();

    if (!big) {
      // ---- lane-per-node attention from LDS ----
      if (tid < nn) {
        float s = 0.f;
#pragma unroll 8
        for (int o = 0; o < 64; ++o) s = fmaf(hvs[tid * 65 + o], qv[o], s);
        ev[tid] = s;
      } else {
        ev[tid] = -INFINITY;
      }
      __syncthreads();
      if (tid < 64) {
        float m4 = fmaxf(fmaxf(ev[tid], ev[64 + tid]), fmaxf(ev[128 + tid], ev[192 + tid]));
#pragma unroll
        for (int s = 32; s; s >>= 1) m4 = fmaxf(m4, __shfl_xor(m4, s));
        if (tid == 0) redM[0] = m4;
      }
      __syncthreads();
      const float m = redM[0];
      float a = 0.f;
      if (tid < nn) { a = expf(ev[tid] - m); av[tid] = a; }
      __syncthreads();          // av writes done before reuse of ev
      ev[tid] = a;
      __syncthreads();
      if (tid < 64) {
        float s4 = ev[tid] + ev[64 + tid] + ev[128 + tid] + ev[192 + tid];
#pragma unroll
        for (int s = 32; s; s >>= 1) s4 += __shfl_xor(s4, s);
        if (tid == 0) redS[0] = s4;
      }
      __syncthreads();
      const float sden = redS[0];
      if (tid < 128) {
        if (tid < 64) {
          qs[tid] = qv[tid];
        } else {
          int o = tid - 64;
          float r = 0.f;
          for (int n = 0; n < nn; ++n) r = fmaf(av[n], hvs[n * 65 + o], r);
          qs[tid] = (nn > 0) ? r / sden : 0.f;
        }
      }
      __syncthreads();
    } else {
      // ---- fallback: global-read path (graphs > CAP nodes; never hit in practice) ----
      const float q = qv[lane];
      float mw = -INFINITY;
      for (int n = beg + wid; n < end; n += 4) {
        float hv = fmaxf((hn2[(size_t)n * 64 + lane] - mu_s[lane]) * rs_s[lane] + bt_s[lane],
                         0.f) + h2[(size_t)n * 64 + lane];
        float p = hv * q;
#pragma unroll
        for (int s = 32; s; s >>= 1) p += __shfl_xor(p, s);
        mw = fmaxf(mw, p);
      }
      if (lane == 0) redM[wid] = mw;
      __syncthreads();
      const float m = fmaxf(fmaxf(redM[0], redM[1]), fmaxf(redM[2], redM[3]));
      float ssum = 0.f, racc = 0.f;
      for (int n = beg + wid; n < end; n += 4) {
        float hv = fmaxf((hn2[(size_t)n * 64 + lane] - mu_s[lane]) * rs_s[lane] + bt_s[lane],
                         0.f) + h2[(size_t)n * 64 + lane];
        float p = hv * q;
#pragma unroll
        for (int s = 32; s; s >>= 1) p += __shfl_xor(p, s);
        float a = expf(p - m);
        ssum += a;
        racc = fmaf(a, hv, racc);
      }
      if (lane == 0) redS[wid] = ssum;
      redR[wid][lane] = racc;
      __syncthreads();
      if (tid < 128) {
        if (tid < 64) {
          qs[tid] = qv[tid];
        } else {
          int o2 = tid - 64;
          float rsum = redR[0][o2] + redR[1][o2] + redR[2][o2] + redR[3][o2];
          float sd = redS[0] + redS[1] + redS[2] + redS[3];
          qs[tid] = (end > beg) ? rsum / sd : 0.0f;
        }
      }
      __syncthreads();
    }
  }

  // ---- regression head (reads final q_star in qs) ----
  if (tid < 64) {
    float a = hb1[tid];
    for (int i = 0; i < 128; ++i) a = fmaf(qs[i], hW1[i * 64 + tid], a);
    z1[tid] = fmaxf(a, 0.0f);
  }
  __syncthreads();
  if (tid < 32) {
    float a2 = hb2[tid];
    for (int i = 0; i < 64; ++i) a2 = fmaf(z1[i], hW2[i * 32 + tid], a2);
    z2[tid] = fmaxf(a2, 0.0f);
  }
  __syncthreads();
  if (tid < 64) {
    float p = (tid < 32) ? z2[tid] * hW3[tid] : 0.0f;
#pragma unroll
    for (int s = 32; s; s >>= 1) p += __shfl_xor(p, s);
    if (tid == 0) out[b] = p + hb3[0];
  }
}

extern "C" void kernel_launch(void* const* d_in, const int* in_sizes, int n_in,
                              void* d_out, int out_size, void* d_ws, size_t ws_size,
                              hipStream_t stream) {
  const float* x = (const float*)d_in[0];
  const int* eidx = (const int*)d_in[1];
  const float* ea = (const float*)d_in[2];
  const int* batch = (const int*)d_in[3];
  const float* Wenc = (const float*)d_in[4];
  const float* benc = (const float*)d_in[5];
  const float* eW1 = (const float*)d_in[6];
  const float* eb1 = (const float*)d_in[7];
  const float* eW2 = (const float*)d_in[8];
  const float* eb2 = (const float*)d_in[9];
  const float* root = (const float*)d_in[10];
  const float* cbias = (const float*)d_in[11];
  const float* gamma = (const float*)d_in[12];
  const float* beta = (const float*)d_in[13];
  const float* Wih = (const float*)d_in[14];
  const float* Whh = (const float*)d_in[15];
  const float* bih = (const float*)d_in[16];
  const float* bhh = (const float*)d_in[17];
  const float* hW1 = (const float*)d_in[18];
  const float* hb1 = (const float*)d_in[19];
  const float* hW2 = (const float*)d_in[20];
  const float* hb2 = (const float*)d_in[21];
  const float* hW3 = (const float*)d_in[22];
  const float* hb3 = (const float*)d_in[23];

  const int N = in_sizes[0] / ND;
  const int E = in_sizes[1] / 2;
  const int B = out_size;
  const int* srcp = eidx;
  const int* dstp = eidx + E;
  const int Etiles = (E + 63) / 64;

  // ---- workspace layout: deg | [zeroed: agg|bnslab] | rest ----
  float* ws = (float*)d_ws;
  float* deg = ws;                                     // N (zeroed by k_zdeg)
  float* agg = deg + N;                                // N*64
  float* bnslab = agg + (size_t)N * 64;                // NL * NSLAB * 128
  const long NZ = (long)((size_t)N * 64 + NL * NSLAB * 128);
  float* h0 = bnslab + NL * NSLAB * 128;               // N*64
  float* h1 = h0 + (size_t)N * 64;                     // N*64
  float* h2 = h1 + (size_t)N * 64;                     // N*64
  float* hn0 = h2 + (size_t)N * 64;                    // N*64
  float* hn1 = hn0 + (size_t)N * 64;                   // N*64
  float* hn2 = hn1 + (size_t)N * 64;                   // N*64
  _Float16* w2P = (_Float16*)(hn2 + (size_t)N * 64);   // 3 * 65*8*64*8 f16
  _Float16* hhalf = w2P + (size_t)3 * 65 * 8 * 64 * 8; // N*64 f16
  float* WihT = (float*)(hhalf + (size_t)N * 64);      // 128*256
  float* WhhT = WihT + 128 * 256;                      // 64*256
  float* gbias = WhhT + 64 * 256;                      // 256
  int* dptr = (int*)(gbias + 256);                     // N+1
  int* cursor = dptr + N + 1;                          // N
  int* perm = cursor + N;                              // E
  int* srcP = perm + E;                                // E
  int* dstP = srcP + E;                                // E
  int* ptr = dstP + E;                                 // B+1

  const int nbEnc = (N * 64 + 255) / 256;
  const int nbDeg = (E + 255) / 256;
  const int nbPtr = (N + 255) / 256;
  const int nbPackW = (192 * 256 + 256 + 255) / 256;
  const int nbPack3 = 130 * NL;
  const int nbZero = (int)((NZ / 4 + 255) / 256);

  k_zdeg<<<(N + 255) / 256, 256, 0, stream>>>(deg, N);
  k_setup<<<nbEnc + nbDeg + nbPtr + nbPackW + nbPack3 + nbZero, 256, 0, stream>>>(
      x, Wenc, benc, h0, hhalf, N, dstp, deg, E, batch, ptr, B,
      Wih, Whh, bih, bhh, WihT, WhhT, gbias, eW2, eb2, w2P, agg, NZ,
      nbEnc, nbDeg, nbPtr, nbPackW, nbPack3);
  k_scan<<<1, 256, 0, stream>>>(deg, dptr, cursor, N);
  k_fill<<<(E + 255) / 256, 256, 0, stream>>>(dstp, srcp, cursor, perm, srcP, dstP, E);

  float* hbuf[3] = {h0, h1, h2};
  float* hnbuf[3] = {hn0, hn1, hn2};
  for (int l = 0; l < NL; ++l) {
    float* slab_l = bnslab + (size_t)l * NSLAB * 128;
    const _Float16* w2_l = w2P + (size_t)l * 65 * 8 * 64 * 8;
    if (l > 0) {
      k_hmat<<<(N * 64 + 255) / 256, 256, 0, stream>>>(
          hnbuf[l - 1], hbuf[l - 1], bnslab + (size_t)(l - 1) * NSLAB * 128,
          gamma + (l - 1) * 64, beta + (l - 1) * 64, hbuf[l], hhalf, N);
    }
    k_msgagg<<<Etiles, 512, 0, stream>>>(ea, perm, eW1 + (size_t)l * ED * 64,
                                         eb1 + (size_t)l * 64, hhalf, srcP, dstP, dptr,
                                         w2_l, agg, E, N);
    k_update<<<(N + 15) / 16, 256, 0, stream>>>(hbuf[l], agg, deg,
                                                root + (size_t)l * 64 * 64,
                                                cbias + l * 64, hnbuf[l], slab_l, N);
  }

  k_s2s_all<<<B, 256, 0, stream>>>(hn2, h2, bnslab + (size_t)2 * NSLAB * 128,
                                   gamma + 2 * 64, beta + 2 * 64, ptr, WihT, WhhT, gbias,
                                   hW1, hb1, hW2, hb2, hW3, hb3, (float*)d_out, N);
}